// Round 3
// baseline (660.881 us; speedup 1.0000x reference)
//
#include <hip/hip_runtime.h>
#include <stdint.h>

typedef unsigned short u16;
typedef unsigned int   u32;
typedef _Float16 f16;
typedef __attribute__((ext_vector_type(2))) _Float16 half2v;
typedef __attribute__((ext_vector_type(8))) _Float16 half8;   // 8 f16 = 4 VGPRs (MFMA A/B frag)
typedef __attribute__((ext_vector_type(4))) float f32x4;      // MFMA C/D frag

#define TPB 192
#define FPB 32            // frames per block; 4000/32=125 -> blocks never straddle batches
#define NB 257
#define LF 513
#define FS 80
#define NCH 9             // K chunks of 32: slots 0..256 = H[0..256], 257..287 = 0
#define MT_TOTAL 33       // 33 tap tiles of 16 = 528 taps (513 real + 15 zero)
#define HROW16 296        // Hlds row stride (u16): 592B, 16B-aligned rows
#define GROW 346          // G row stride (u32): 1384B, 8B-aligned rows, bank-stride 26 (near-odd)
#define NROW 44           // noise row stride (u32): 176B, 16B-aligned rows
#define TAB_ELEMS (MT_TOTAL*NCH*64*8)

__device__ __forceinline__ u32 pk2(float a, float b){  // pack 2 f32 -> f16 pair (lo=a, hi=b)
  return __builtin_bit_cast(u32, __builtin_amdgcn_cvt_pkrtz(a, b));
}
__device__ __forceinline__ float dot2(u32 a, u32 b, float c){
#if __has_builtin(__builtin_amdgcn_fdot2)
  return __builtin_amdgcn_fdot2(__builtin_bit_cast(half2v, a), __builtin_bit_cast(half2v, b), c, false);
#else
  half2v x = __builtin_bit_cast(half2v, a), y = __builtin_bit_cast(half2v, b);
  return fmaf((float)x[1], (float)y[1], fmaf((float)x[0], (float)y[0], c));
#endif
}

// ---------------------------------------------------------------------------
// Table in exact MFMA A-frag order: elem((mt*9+c)*64+lane, j) = A[tap][kslot],
// tap = mt*16+(lane&15), kslot = c*32+(lane>>4)*8+j.
// kslot==0 -> coeff of H[0] = hann/513; 1<=kslot<=256 -> (2/513)*hann*cos(2pi*k*(tap-256)/513).
// N=513 odd => all bins k=1..256 are doubled (no Nyquist special case).
// ---------------------------------------------------------------------------
__global__ void build_table(u16* __restrict__ tab){
  int id = blockIdx.x * blockDim.x + threadIdx.x;
  if (id >= TAB_ELEMS) return;
  int j    = id & 7;
  int lane = (id >> 3) & 63;
  int cc   = (id >> 9) % NCH;
  int mt   = (id >> 9) / NCH;
  int tap  = mt * 16 + (lane & 15);
  int kslot= cc * 32 + (lane >> 4) * 8 + j;
  float val = 0.f;
  if (tap < LF){
    float hann = 0.5f - 0.5f * cosf(6.28318530717958647f * (float)tap / 513.f);
    if (kslot == 0){
      val = hann * (1.f / 513.f);
    } else if (kslot <= 256){
      int rr = (kslot * (tap + 257)) % 513;     // k*(tap-256) mod 513
      val = (2.f / 513.f) * hann * cosf((float)rr * (6.28318530717958647f / 513.f));
    }
  }
  f16 h = (f16)val;
  tab[id] = __builtin_bit_cast(u16, h);
}

// ---------------------------------------------------------------------------
// Fused: stage H/noise(f16) -> MFMA GEMM (fir = T*H^T) -> reversed fir in LDS
// (G[i] = fir_ext[607-i]) -> dot2 conv + OLA. out[j] = sum_n noise[n]*G[(607-j)+n].
// ---------------------------------------------------------------------------
__launch_bounds__(TPB, 3)
__global__ void fused(const float* __restrict__ Hg, const float* __restrict__ noiseg,
                      const u16* __restrict__ tab, float* __restrict__ out){
  __shared__ __align__(16) u32 Gu[FPB * GROW];   // GEMM phase: aliases Hlds u16[32][296]
  __shared__ __align__(16) u32 Nu[FPB * NROW];   // per frame: nA[0..40], [41]=pack(0,n0), [42..43]=0

  const int tid  = threadIdx.x;
  const int lane = tid & 63;
  const int w    = tid >> 6;          // 3 waves
  const int ln15 = lane & 15;
  const int q    = lane >> 4;
  const int blk  = blockIdx.x;
  const int f0   = blk * FPB;

  u16* Hlds = (u16*)Gu;               // [32][296]: slot s = f16(H[s]) s=0..256; 257..287 = 0

  // ---- stage H: 32 rows x 144 u32 tasks ----
  #pragma unroll
  for (int e = 0; e < 24; ++e){
    int id = tid + TPB * e;
    int r = id / 144, p = id % 144;
    const float* gp = Hg + (size_t)(f0 + r) * NB;
    u32 v = 0u;
    if (p < 128)       v = pk2(gp[2*p], gp[2*p+1]);
    else if (p == 128) v = pk2(gp[256], 0.f);
    *(u32*)&Hlds[r * HROW16 + 2 * p] = v;
  }
  // ---- stage noise: u*2-1 as f16 pairs ----
  #pragma unroll
  for (int e = 0; e < 7; ++e){
    int id = tid + TPB * e;
    if (id < FPB * 40){
      int r = id / 40, m = id % 40;
      const float* np = noiseg + (size_t)(f0 + r) * FS + 2 * m;
      Nu[r * NROW + m] = pk2(np[0] * 2.f - 1.f, np[1] * 2.f - 1.f);
    }
  }
  if (tid < FPB){
    float n0 = noiseg[(size_t)(f0 + tid) * FS] * 2.f - 1.f;
    Nu[tid * NROW + 40] = 0u;
    Nu[tid * NROW + 41] = pk2(0.f, n0);   // hi half = n0 (odd-output n=0 correction)
    Nu[tid * NROW + 42] = 0u;
    Nu[tid * NROW + 43] = 0u;
  }
  __syncthreads();

  // ---- GEMM: fir[tap][frame] = sum_k T[tap][k]*H[frame][k]; 3 waves x 11 mt x 2 nt ----
  f32x4 acc[11][2];
  #pragma unroll
  for (int a = 0; a < 11; ++a){ acc[a][0] = (f32x4){0,0,0,0}; acc[a][1] = (f32x4){0,0,0,0}; }
  const half8* tab8 = (const half8*)tab;
  for (int c = 0; c < NCH; ++c){
    half8 bfrag[2];
    #pragma unroll
    for (int nt = 0; nt < 2; ++nt)
      bfrag[nt] = *(const half8*)&Hlds[(nt*16 + ln15) * HROW16 + c*32 + q*8];
    #pragma unroll
    for (int mm = 0; mm < 11; ++mm){
      half8 afrag = tab8[((w*11 + mm) * NCH + c) * 64 + lane];
      #pragma unroll
      for (int nt = 0; nt < 2; ++nt)
        acc[mm][nt] = __builtin_amdgcn_mfma_f32_16x16x32_f16(afrag, bfrag[nt], acc[mm][nt], 0, 0, 0);
    }
  }
  __syncthreads();   // done reading Hlds; region becomes G

  // ---- epilogue: C/D (col=frame, row=q*4+reg=tap) -> G reversed f16 pairs ----
  // pair p0=302-t0/2 = (fir[t0+3],fir[t0+2]); p1 = (fir[t0+1],fir[t0]) — both in-lane.
  #pragma unroll
  for (int mm = 0; mm < 11; ++mm){
    int t0 = (w*11 + mm)*16 + q*4;
    #pragma unroll
    for (int nt = 0; nt < 2; ++nt){
      int frame = nt*16 + ln15;
      f32x4 v = acc[mm][nt];
      uint2 pk;
      pk.x = pk2(v.w, v.z);
      pk.y = pk2(v.y, v.x);
      *(uint2*)&Gu[frame * GROW + (302 - (t0 >> 1))] = pk;
    }
  }
  // zero-fill pads: u32 slots [0,40) and [304,346) per row
  #pragma unroll
  for (int e = 0; e < 14; ++e){
    int id = tid + TPB * e;
    if (id < FPB * 82){
      int r = id / 82, s2 = id % 82;
      Gu[r * GROW + (s2 < 40 ? s2 : 264 + s2)] = 0u;
    }
  }
  __syncthreads();

  // ---- conv + OLA: thread T -> 16 outputs (block-rel samples 16T..16T+15) ----
  const bool lastB = (blk % 125) == 124;   // tail spills past batch trim -> skip
  if (!(tid >= 160 && lastB)){
    const int s    = tid % 5;              // j0min = 16*s
    const int fTop = tid / 5;
    const int dMax = (s <= 2) ? 7 : 6;     // keep j0 <= 592 so G index >= 0
    float ac[16];
    #pragma unroll
    for (int r = 0; r < 16; ++r) ac[r] = 0.f;

    #pragma unroll 1
    for (int d = 0; d <= 7; ++d){
      const int frel = fTop - d;
      if (d <= dMax && frel >= 0 && frel < FPB){
        const u32* Gr = Gu + frel * GROW;
        const u32* Nr = Nu + frel * NROW;
        const int V = 304 - 8*s - 40*d;    // top pair start; V%8==0 -> 8B-aligned loads
        u32 W[12];
        { uint2 a0 = *(const uint2*)(Gr + V - 8);
          uint2 a1 = *(const uint2*)(Gr + V - 6);
          uint2 a2 = *(const uint2*)(Gr + V - 4);
          uint2 a3 = *(const uint2*)(Gr + V - 2);
          W[0]=a0.x; W[1]=a0.y; W[2]=a1.x; W[3]=a1.y; W[4]=a2.x; W[5]=a2.y; W[6]=a3.x; W[7]=a3.y; }
        const u32 n0hi = Nr[41];
        #pragma unroll
        for (int k = 0; k < 8; ++k)        // n=0 correction for even r (odd beta)
          ac[2*k] = dot2(n0hi, W[7-k], ac[2*k]);
        uint4 naNext = *(const uint4*)(Nr);
        #pragma unroll
        for (int c = 0; c < 10; ++c){
          uint2 g0 = *(const uint2*)(Gr + V + 4*c);
          uint2 g1 = *(const uint2*)(Gr + V + 4*c + 2);
          W[8] = g0.x; W[9] = g0.y; W[10] = g1.x; W[11] = g1.y;
          uint4 naCur = naNext;
          naNext = *(const uint4*)(Nr + 4*c + 4);       // c=9 reads slots 40..43 (padded)
          u32 nAv[5] = {naCur.x, naCur.y, naCur.z, naCur.w, naNext.x};
          #pragma unroll
          for (int i = 0; i < 4; ++i){
            u32 a   = nAv[i];                                        // (n[2m], n[2m+1])
            u32 sft = __builtin_amdgcn_alignbit(nAv[i+1], nAv[i], 16); // (n[2m+1], n[2m+2])
            #pragma unroll
            for (int k = 0; k < 8; ++k){
              ac[2*k]   = dot2(sft, W[i+8-k], ac[2*k]);
              ac[2*k+1] = dot2(a,   W[i+7-k], ac[2*k+1]);
            }
          }
          #pragma unroll
          for (int p = 0; p < 8; ++p) W[p] = W[p+4];
        }
      }
    }
    const size_t s0 = (size_t)blk * 2560 + (size_t)tid * 16;  // flat == batched index
    if (tid >= 32 && tid < 160){           // interior: single-owner vector stores
      *(float4*)&out[s0]      = make_float4(ac[0], ac[1], ac[2], ac[3]);
      *(float4*)&out[s0 + 4]  = make_float4(ac[4], ac[5], ac[6], ac[7]);
      *(float4*)&out[s0 + 8]  = make_float4(ac[8], ac[9], ac[10], ac[11]);
      *(float4*)&out[s0 + 12] = make_float4(ac[12], ac[13], ac[14], ac[15]);
    } else {                               // fringes shared with neighbor blocks
      #pragma unroll
      for (int r = 0; r < 16; ++r) atomicAdd(&out[s0 + r], ac[r]);
    }
  }
}

extern "C" void kernel_launch(void* const* d_in, const int* in_sizes, int n_in,
                              void* d_out, int out_size, void* d_ws, size_t ws_size,
                              hipStream_t stream){
  const float* Hg     = (const float*)d_in[0];   // [32,4000,257] fp32
  const float* noiseg = (const float*)d_in[1];   // [32,4000,80]  fp32
  float* out = (float*)d_out;                    // [32,320000]   fp32
  u16* tab = (u16*)d_ws;                         // 304128 B

  hipMemsetAsync(d_out, 0, (size_t)out_size * sizeof(float), stream);
  build_table<<<TAB_ELEMS / 256, 256, 0, stream>>>(tab);
  fused<<<(32 * 4000) / FPB, TPB, 0, stream>>>(Hg, noiseg, tab, out);
}

// Round 4
// 469.154 us; speedup vs baseline: 1.4087x; 1.4087x over previous
//
#include <hip/hip_runtime.h>
#include <stdint.h>

typedef unsigned short u16;
typedef unsigned int   u32;
typedef _Float16 f16;
typedef __attribute__((ext_vector_type(2))) _Float16 half2v;
typedef __attribute__((ext_vector_type(8))) _Float16 half8;   // 8 f16 = 4 VGPRs (MFMA A/B frag)
typedef __attribute__((ext_vector_type(4))) float f32x4;      // MFMA C/D frag

#define TPB 384           // 6 waves; 3 blocks/CU (LDS-capped) = 18 waves/CU
#define FPB 32            // frames per block; 4000/32=125 -> blocks never straddle batches
#define NB 257
#define LF 513
#define FS 80
#define NCH 9             // K chunks of 32: slots 0..256 = H[0..256], 257..287 = 0
#define MT_TOTAL 33       // 33 tap tiles of 16 = 528 taps (513 real + 15 zero)
#define HROW16 296        // Hlds row stride (u16): 592B, 16B-aligned rows
#define GROW 348          // G row stride (u32): 1392B -> 16B-aligned rows (uint4 conv loads)
#define NROW 44           // noise row stride (u32): 176B, 16B-aligned rows
#define TAB_ELEMS (MT_TOTAL*NCH*64*8)

__device__ __forceinline__ u32 pk2(float a, float b){  // pack 2 f32 -> f16 pair (lo=a, hi=b)
  return __builtin_bit_cast(u32, __builtin_amdgcn_cvt_pkrtz(a, b));
}
__device__ __forceinline__ float dot2(u32 a, u32 b, float c){
#if __has_builtin(__builtin_amdgcn_fdot2)
  return __builtin_amdgcn_fdot2(__builtin_bit_cast(half2v, a), __builtin_bit_cast(half2v, b), c, false);
#else
  half2v x = __builtin_bit_cast(half2v, a), y = __builtin_bit_cast(half2v, b);
  return fmaf((float)x[1], (float)y[1], fmaf((float)x[0], (float)y[0], c));
#endif
}

// ---------------------------------------------------------------------------
// Table in exact MFMA A-frag order: elem((mt*9+c)*64+lane, j) = A[tap][kslot],
// tap = mt*16+(lane&15), kslot = c*32+(lane>>4)*8+j.
// kslot==0 -> hann/513; 1<=kslot<=256 -> (2/513)*hann*cos(2pi*k*(tap-256)/513).
// ---------------------------------------------------------------------------
__global__ void build_table(u16* __restrict__ tab){
  int id = blockIdx.x * blockDim.x + threadIdx.x;
  if (id >= TAB_ELEMS) return;
  int j    = id & 7;
  int lane = (id >> 3) & 63;
  int cc   = (id >> 9) % NCH;
  int mt   = (id >> 9) / NCH;
  int tap  = mt * 16 + (lane & 15);
  int kslot= cc * 32 + (lane >> 4) * 8 + j;
  float val = 0.f;
  if (tap < LF){
    float hann = 0.5f - 0.5f * cosf(6.28318530717958647f * (float)tap / 513.f);
    if (kslot == 0){
      val = hann * (1.f / 513.f);
    } else if (kslot <= 256){
      int rr = (kslot * (tap + 257)) % 513;     // k*(tap-256) mod 513
      val = (2.f / 513.f) * hann * cosf((float)rr * (6.28318530717958647f / 513.f));
    }
  }
  f16 h = (f16)val;
  tab[id] = __builtin_bit_cast(u16, h);
}

// ---------------------------------------------------------------------------
// Fused: stage H/noise(f16) -> MFMA GEMM (fir = T*H^T) -> reversed fir in LDS
// (G[g] = fir_ext[607-g]) -> dot2 conv + OLA. out[j] = sum_n noise[n]*G[607-j+n].
// ---------------------------------------------------------------------------
__launch_bounds__(TPB, 5)
__global__ void fused(const float* __restrict__ Hg, const float* __restrict__ noiseg,
                      const u16* __restrict__ tab, float* __restrict__ out){
  __shared__ __align__(16) u32 Gu[FPB * GROW];   // GEMM phase: aliases Hlds u16[32][296]
  __shared__ __align__(16) u32 Nu[FPB * NROW];   // per frame: nA[0..40], [41]=pack(0,n0), [42..43]=0

  const int tid  = threadIdx.x;
  const int lane = tid & 63;
  const int w    = tid >> 6;          // 6 waves
  const int ln15 = lane & 15;
  const int q    = lane >> 4;
  const int blk  = blockIdx.x;
  const int f0   = blk * FPB;

  u16* Hlds = (u16*)Gu;               // [32][296]: slot s = f16(H[s]) s=0..256; 257..287 = 0

  // ---- stage H: 32 rows x 144 u32 tasks = 4608 = 12*384 ----
  #pragma unroll
  for (int e = 0; e < 12; ++e){
    int id = tid + TPB * e;
    int r = id / 144, p = id % 144;
    const float* gp = Hg + (size_t)(f0 + r) * NB;
    u32 v = 0u;
    if (p < 128)       v = pk2(gp[2*p], gp[2*p+1]);
    else if (p == 128) v = pk2(gp[256], 0.f);
    *(u32*)&Hlds[r * HROW16 + 2 * p] = v;
  }
  // ---- stage noise: u*2-1 as f16 pairs (1280 tasks) ----
  #pragma unroll
  for (int e = 0; e < 4; ++e){
    int id = tid + TPB * e;
    if (id < FPB * 40){
      int r = id / 40, m = id % 40;
      const float* np = noiseg + (size_t)(f0 + r) * FS + 2 * m;
      Nu[r * NROW + m] = pk2(np[0] * 2.f - 1.f, np[1] * 2.f - 1.f);
    }
  }
  if (tid < FPB){
    float n0 = noiseg[(size_t)(f0 + tid) * FS] * 2.f - 1.f;
    Nu[tid * NROW + 40] = 0u;
    Nu[tid * NROW + 41] = pk2(0.f, n0);   // hi half = n0 (even-output n=0 correction)
    Nu[tid * NROW + 42] = 0u;
    Nu[tid * NROW + 43] = 0u;
  }
  __syncthreads();

  // ---- GEMM: fir[tap][frame] = sum_k T[tap][k]*H[frame][k]; 6 waves: {6,6,6,5,5,5} mt ----
  const int base = (w < 3) ? 6 * w : 18 + 5 * (w - 3);
  const int cnt  = (w < 3) ? 6 : 5;
  f32x4 acc[6][2];
  #pragma unroll
  for (int a = 0; a < 6; ++a){ acc[a][0] = (f32x4){0,0,0,0}; acc[a][1] = (f32x4){0,0,0,0}; }
  const half8* tab8 = (const half8*)tab;
  for (int c = 0; c < NCH; ++c){
    half8 bfrag[2];
    #pragma unroll
    for (int nt = 0; nt < 2; ++nt)
      bfrag[nt] = *(const half8*)&Hlds[(nt*16 + ln15) * HROW16 + c*32 + q*8];
    #pragma unroll
    for (int mm = 0; mm < 6; ++mm){
      if (mm < cnt){
        half8 afrag = tab8[((base + mm) * NCH + c) * 64 + lane];
        #pragma unroll
        for (int nt = 0; nt < 2; ++nt)
          acc[mm][nt] = __builtin_amdgcn_mfma_f32_16x16x32_f16(afrag, bfrag[nt], acc[mm][nt], 0, 0, 0);
      }
    }
  }
  __syncthreads();   // done reading Hlds; region becomes G

  // ---- epilogue: C/D (col=frame, row=q*4+reg=tap) -> G reversed f16 pairs ----
  #pragma unroll
  for (int mm = 0; mm < 6; ++mm){
    if (mm < cnt){
      int t0 = (base + mm)*16 + q*4;
      #pragma unroll
      for (int nt = 0; nt < 2; ++nt){
        int frame = nt*16 + ln15;
        f32x4 v = acc[mm][nt];
        uint2 pk;
        pk.x = pk2(v.w, v.z);
        pk.y = pk2(v.y, v.x);
        *(uint2*)&Gu[frame * GROW + (302 - (t0 >> 1))] = pk;   // G[g]=fir[607-g]
      }
    }
  }
  // zero-fill pads: u32 slots [0,40) and [304,348) per row = 84/row -> 2688 = 7*384
  #pragma unroll
  for (int e = 0; e < 7; ++e){
    int id = tid + TPB * e;
    int r = id / 84, s2 = id % 84;
    Gu[r * GROW + (s2 < 40 ? s2 : 264 + s2)] = 0u;
  }
  __syncthreads();

  // ---- conv + OLA: thread tid -> 8 outputs (block-rel samples 8*tid..8*tid+7) ----
  const bool lastB = (blk % 125) == 124;   // right spill past batch trim -> skip
  if (!(tid >= 320 && lastB)){
    const int s8   = tid % 10;             // j0 = 8*s8 + 80*d
    const int fTop = tid / 10;
    const int dMax = (s8 <= 3) ? 7 : 6;    // keep j0 <= 584
    float ac[8];
    #pragma unroll
    for (int r = 0; r < 8; ++r) ac[r] = 0.f;

    #pragma unroll 1
    for (int d = 0; d <= 7; ++d){
      const int frel = fTop - d;
      if (d <= dMax && frel >= 0 && frel < FPB){
        const u32* Gr = Gu + frel * GROW;
        const u32* Nr = Nu + frel * NROW;
        const int V = 304 - 4*s8 - 40*d;   // top pair; V%4==0 -> all uint4 loads 16B-aligned
        u32 W[12];                          // slots 4..11: W[p] = G pair (V + 4c - 8 + p)
        { uint4 a0 = *(const uint4*)(Gr + V - 4);
          W[4]=a0.x; W[5]=a0.y; W[6]=a0.z; W[7]=a0.w; }
        const u32 n0hi = Nr[41];
        #pragma unroll
        for (int k = 0; k < 4; ++k)        // n=0 correction for even r
          ac[2*k] = dot2(n0hi, W[7-k], ac[2*k]);
        uint4 naNext = *(const uint4*)(Nr);
        #pragma unroll
        for (int c = 0; c < 10; ++c){
          uint4 g = *(const uint4*)(Gr + V + 4*c);
          W[8] = g.x; W[9] = g.y; W[10] = g.z; W[11] = g.w;
          uint4 naCur = naNext;
          naNext = *(const uint4*)(Nr + 4*c + 4);       // c=9 reads slots 40..43 (padded)
          u32 nAv[5] = {naCur.x, naCur.y, naCur.z, naCur.w, naNext.x};
          #pragma unroll
          for (int i = 0; i < 4; ++i){
            u32 a   = nAv[i];                                          // (n[2m], n[2m+1])
            u32 sft = __builtin_amdgcn_alignbit(nAv[i+1], nAv[i], 16); // (n[2m+1], n[2m+2])
            #pragma unroll
            for (int k = 0; k < 4; ++k){
              ac[2*k]   = dot2(sft, W[i+8-k], ac[2*k]);
              ac[2*k+1] = dot2(a,   W[i+7-k], ac[2*k+1]);
            }
          }
          W[4] = W[8]; W[5] = W[9]; W[6] = W[10]; W[7] = W[11];
        }
      }
    }
    const size_t s0 = (size_t)blk * 2560 + (size_t)tid * 8;  // flat == batched index
    if (tid >= 64 && tid < 320){           // interior: single-owner vector stores
      *(float4*)&out[s0]     = make_float4(ac[0], ac[1], ac[2], ac[3]);
      *(float4*)&out[s0 + 4] = make_float4(ac[4], ac[5], ac[6], ac[7]);
    } else {                               // fringes shared with neighbor blocks
      #pragma unroll
      for (int r = 0; r < 8; ++r) atomicAdd(&out[s0 + r], ac[r]);
    }
  }
}

extern "C" void kernel_launch(void* const* d_in, const int* in_sizes, int n_in,
                              void* d_out, int out_size, void* d_ws, size_t ws_size,
                              hipStream_t stream){
  const float* Hg     = (const float*)d_in[0];   // [32,4000,257] fp32
  const float* noiseg = (const float*)d_in[1];   // [32,4000,80]  fp32
  float* out = (float*)d_out;                    // [32,320000]   fp32
  u16* tab = (u16*)d_ws;                         // 304128 B

  hipMemsetAsync(d_out, 0, (size_t)out_size * sizeof(float), stream);
  build_table<<<TAB_ELEMS / 256, 256, 0, stream>>>(tab);
  fused<<<(32 * 4000) / FPB, TPB, 0, stream>>>(Hg, noiseg, tab, out);
}